// Round 3
// baseline (120.666 us; speedup 1.0000x reference)
//
#include <hip/hip_runtime.h>

// SparsePropMaxPool closed form (verified rounds 1-2, absmax=0):
//   ori_map_h[b,h,s,e] = max(x[b,h,s..e]) if (s, d=e-s) in SET else 0
//   SET: d in [0,15] any s | d odd in [17,31], s even | d%4==3 in [35,63], s%4==0
//   props_h[b,p,h] = max(x[b,h, s_p .. s_p+d_p])  (153 constant ranges)
//   mask[b,0,s,e] = 1 at SET positions
// Out layout: props (64*153*512) | map (64*512*64*64) | mask (64*64*64)
// Single fused kernel: every block maps 8 bh-rows; 1/8 of blocks also emit the
// props for their (b, h-chunk) first (hides under the map-store BW of the rest).

#define B_ 64
#define H_ 512
#define N_ 64
#define NPROP 153

__device__ __forceinline__ bool in_set(int s, int d) {
    if (d < 0) return false;
    if (d <= 15) return true;
    if (d <= 31) return (d & 1) && ((s & 1) == 0);        // d=17,19..31 odd, s even
    return (d >= 35) && ((d & 3) == 3) && ((s & 3) == 0); // d=35,39..63, s%4==0
}

__global__ __launch_bounds__(128) void fused_kernel(const float* __restrict__ x,
                                                    float* __restrict__ out_props,
                                                    float* __restrict__ out_map,
                                                    float* __restrict__ out_mask) {
    const int lane = threadIdx.x;   // 0..127
    const int bid  = blockIdx.x;    // 0..4095

    // ---------- props (+mask) prologue: blocks with bid%8==0 ----------
    if ((bid & 7) == 0) {
        const int b  = bid >> 6;           // batch
        const int m  = (bid >> 3) & 7;     // h-chunk 0..7
        const int h  = m * 64 + (lane & 63);
        const int q  = lane >> 6;          // wave id: splits the 153 queries

        const float4* xr = reinterpret_cast<const float4*>(x + ((size_t)b * H_ + h) * N_);
        float r[64];
        #pragma unroll
        for (int k = 0; k < 16; ++k) {
            float4 v = xr[k];
            r[4*k+0] = v.x; r[4*k+1] = v.y; r[4*k+2] = v.z; r[4*k+3] = v.w;
        }
        float a[63];
        #pragma unroll
        for (int i = 0; i < 63; ++i) a[i] = fmaxf(r[i], r[i+1]);
        float bb[61];
        #pragma unroll
        for (int i = 0; i < 61; ++i) bb[i] = fmaxf(a[i], a[i+2]);
        float T3[57];   // T3[i] = max(x[i..i+7])
        #pragma unroll
        for (int i = 0; i < 57; ++i) T3[i] = fmaxf(bb[i], bb[i+4]);

        float* po = out_props + (size_t)b * NPROP * H_ + h;
        if (q == 0) {   // wave 0: p = 0..76  (d=7 all, d=15 s<20)
            #pragma unroll
            for (int s = 0; s < 57; ++s)
                po[(size_t)s * H_] = T3[s];
            #pragma unroll
            for (int s = 0; s < 20; ++s)
                po[(size_t)(57 + s) * H_] = fmaxf(T3[s], T3[s + 8]);
        } else {        // wave 1: p = 77..152
            #pragma unroll
            for (int s = 20; s < 49; ++s)
                po[(size_t)(57 + s) * H_] = fmaxf(T3[s], T3[s + 8]);
            int p = 106;
            #pragma unroll
            for (int s = 0; s <= 40; s += 2)          // d=23
                po[(size_t)(p++) * H_] = fmaxf(fmaxf(T3[s], T3[s + 8]), T3[s + 16]);
            #pragma unroll
            for (int s = 0; s <= 32; s += 2)          // d=31
                po[(size_t)(p++) * H_] =
                    fmaxf(fmaxf(T3[s], T3[s + 8]), fmaxf(T3[s + 16], T3[s + 24]));
            #pragma unroll
            for (int s = 0; s <= 16; s += 4) {        // d=47
                float mx = T3[s];
                #pragma unroll
                for (int j = 8; j <= 40; j += 8) mx = fmaxf(mx, T3[s + j]);
                po[(size_t)(p++) * H_] = mx;
            }
            #pragma unroll
            for (int s = 0; s <= 8; s += 4) {         // d=55
                float mx = T3[s];
                #pragma unroll
                for (int j = 8; j <= 48; j += 8) mx = fmaxf(mx, T3[s + j]);
                po[(size_t)(p++) * H_] = mx;
            }
            {                                         // d=63
                float mx = T3[0];
                #pragma unroll
                for (int j = 8; j <= 56; j += 8) mx = fmaxf(mx, T3[j]);
                po[(size_t)p * H_] = mx;
            }
        }

        if (m == 0) {   // mask: one block per b; both waves, 32 rows each
            float* mk = out_mask + (size_t)b * (N_ * N_);
            const int e = lane & 63;
            #pragma unroll
            for (int i = 0; i < 32; ++i) {
                int s = 2 * i + q;
                mk[s * N_ + e] = in_set(s, e - s) ? 1.0f : 0.0f;
            }
        }
    }

    // ---------- map: all blocks, 8 rows each, float4 stores ----------
    const int g = lane >> 4;          // row within block 0..7
    const int t = lane & 15;          // float4 column 0..15
    const size_t bh = (size_t)bid * 8 + g;

    __shared__ __align__(16) float xs[8][72];   // 288B row pitch: conflict-free
    float4 xv = reinterpret_cast<const float4*>(x)[bid * 128 + lane];
    *reinterpret_cast<float4*>(&xs[g][4 * t]) = xv;
    __syncthreads();

    float4* mrow = reinterpret_cast<float4*>(out_map + bh * (size_t)(N_ * N_));
    const int e0 = 4 * t;
    float vx = 0.f, vy = 0.f, vz = 0.f, vw = 0.f;
    #pragma unroll
    for (int s = N_ - 1; s >= 0; --s) {   // v_j = max(x[s..e_j]), reset at s==e_j
        const float mv = xs[g][s];
        vx = (s == e0 + 0) ? mv : fmaxf(vx, mv);
        vy = (s == e0 + 1) ? mv : fmaxf(vy, mv);
        vz = (s == e0 + 2) ? mv : fmaxf(vz, mv);
        vw = (s == e0 + 3) ? mv : fmaxf(vw, mv);
        float4 w;
        w.x = in_set(s, e0 + 0 - s) ? vx : 0.f;
        w.y = in_set(s, e0 + 1 - s) ? vy : 0.f;
        w.z = in_set(s, e0 + 2 - s) ? vz : 0.f;
        w.w = in_set(s, e0 + 3 - s) ? vw : 0.f;
        mrow[s * 16 + t] = w;              // 4 rows x 256B per wave-instruction
    }
}

extern "C" void kernel_launch(void* const* d_in, const int* in_sizes, int n_in,
                              void* d_out, int out_size, void* d_ws, size_t ws_size,
                              hipStream_t stream) {
    const float* x = (const float*)d_in[0];   // (64, 512, 64) f32
    float* out       = (float*)d_out;
    float* out_props = out;                                   // 5,013,504
    float* out_map   = out + (size_t)B_ * NPROP * H_;         // 134,217,728
    float* out_mask  = out_map + (size_t)B_ * H_ * N_ * N_;   // 262,144

    fused_kernel<<<dim3(B_ * H_ / 8), dim3(128), 0, stream>>>(x, out_props, out_map, out_mask);
}